// Round 2
// baseline (605.215 us; speedup 1.0000x reference)
//
#include <hip/hip_runtime.h>
#include <hip/hip_bf16.h>

// Problem constants
#define B_  128
#define T_  512
#define D_  400
#define NV  1024
#define NA  128

// Main-kernel tiling
#define KP   416   // K padded to 13*32
#define LDH  424   // LDS row stride (bf16 elems): 848B rows, 16B-aligned, banks spread
#define NT   64    // t-tile
#define MV   64    // v rows per block (4 waves x 16)

typedef __bf16 bf16_t;
typedef bf16_t bf16x8 __attribute__((ext_vector_type(8)));
typedef bf16_t bf16x4 __attribute__((ext_vector_type(4)));
typedef float  floatx4 __attribute__((ext_vector_type(4)));

// ---------------------------------------------------------------------------
// Kernel 1: hw[b,t] = H[b,t,:] . W  (one wave per row)
// ---------------------------------------------------------------------------
__global__ __launch_bounds__(256) void hw_kernel(const float* __restrict__ H,
                                                 const float* __restrict__ W,
                                                 float* __restrict__ hw) {
    int wave = threadIdx.x >> 6;
    int lane = threadIdx.x & 63;
    long row = (long)blockIdx.x * 4 + wave;          // row in [0, B*T)
    const float* h = H + row * D_;
    float acc = 0.f;
    for (int k = lane; k < D_; k += 64) acc += h[k] * W[k];
#pragma unroll
    for (int off = 1; off < 64; off <<= 1) acc += __shfl_xor(acc, off, 64);
    if (lane == 0) hw[row] = acc;
}

// ---------------------------------------------------------------------------
// Kernel 2: per-b acts softmax -> q_acts[b,:] into workspace
// ---------------------------------------------------------------------------
__global__ __launch_bounds__(256) void acts_kernel(const float* __restrict__ Ca,
                                                   const float* __restrict__ cu,
                                                   float* __restrict__ q_ws) {
    __shared__ float c_lds[D_];
    __shared__ float p_lds[NA];
    int b = blockIdx.x;
    int tid = threadIdx.x, wave = tid >> 6, lane = tid & 63;

    for (int d = tid; d < D_; d += 256) c_lds[d] = cu[b * D_ + d];
    __syncthreads();

    const float* Cb = Ca + (size_t)b * NA * D_;
    for (int a = wave * 32; a < wave * 32 + 32; ++a) {
        float acc = 0.f;
        for (int k = lane; k < D_; k += 64) acc += Cb[(size_t)a * D_ + k] * c_lds[k];
#pragma unroll
        for (int off = 1; off < 64; off <<= 1) acc += __shfl_xor(acc, off, 64);
        if (lane == 0) p_lds[a] = acc;
    }
    __syncthreads();

    if (tid < 64) {
        float v0 = p_lds[tid], v1 = p_lds[tid + 64];
        float m = fmaxf(v0, v1);
#pragma unroll
        for (int off = 1; off < 64; off <<= 1) m = fmaxf(m, __shfl_xor(m, off, 64));
        float e0 = __expf(v0 - m), e1 = __expf(v1 - m);
        float s = e0 + e1;
#pragma unroll
        for (int off = 1; off < 64; off <<= 1) s += __shfl_xor(s, off, 64);
        p_lds[tid] = e0 / s;
        p_lds[tid + 64] = e1 / s;
    }
    __syncthreads();

    for (int d = tid; d < D_; d += 256) {
        float acc = 0.f;
#pragma unroll 8
        for (int a = 0; a < NA; ++a) acc += p_lds[a] * Cb[(size_t)a * D_ + d];
        q_ws[b * D_ + d] = acc;
    }
}

// ---------------------------------------------------------------------------
// Kernel 3: y_acts[b,v] = q_acts[b,:] . vals[v,:]   (second half of d_out, f32)
// ---------------------------------------------------------------------------
__global__ __launch_bounds__(256) void yacts_kernel(const float* __restrict__ q_ws,
                                                    const float* __restrict__ Cv,
                                                    float* __restrict__ out) {
    __shared__ __align__(16) float q_lds[D_];
    int b = blockIdx.y;
    int v = blockIdx.x * 256 + threadIdx.x;
    for (int d = threadIdx.x; d < D_; d += 256) q_lds[d] = q_ws[b * D_ + d];
    __syncthreads();

    const float4* vr = (const float4*)(Cv + (size_t)v * D_);
    const float4* qr = (const float4*)q_lds;
    float ax = 0.f, ay = 0.f, az = 0.f, aw = 0.f;
#pragma unroll 4
    for (int j = 0; j < D_ / 4; ++j) {
        float4 x = vr[j], y = qr[j];
        ax += x.x * y.x; ay += x.y * y.y; az += x.z * y.z; aw += x.w * y.w;
    }
    out[(size_t)B_ * NV + (size_t)b * NV + v] = ax + ay + az + aw;
}

// ---------------------------------------------------------------------------
// Main kernel: flash-style scalar-value attention.
// Block = (b, 64-v chunk). 4 waves x 16 v-rows. Loop t in tiles of 64.
// S = vals(bf16) @ H^T(bf16) via mfma_f32_16x16x32_bf16; online softmax with
// per-row (m,l,acc); value is the precomputed scalar hw[b,t]. Output f32.
// ---------------------------------------------------------------------------
__global__ __launch_bounds__(256, 2) void main_kernel(const float* __restrict__ H,
                                                      const float* __restrict__ Cv,
                                                      const float* __restrict__ hw,
                                                      const float* __restrict__ bs,
                                                      const int* __restrict__ lens,
                                                      float* __restrict__ out) {
    __shared__ bf16_t h_lds[NT * LDH];
    __shared__ float hw_lds[NT];

    // XCD swizzle: 16 v-chunks of the same b land on the same XCD (round-robin
    // heuristic), so H[b] (819 KB) stays L2-resident across re-reads.
    int i = blockIdx.x;
    int xcd = i & 7, vc = (i >> 3) & 15, bb = i >> 7;
    int b = xcd + 8 * bb;
    int vbase = vc * MV;

    int tid = threadIdx.x;
    int wave = tid >> 6, lane = tid & 63;
    int lrow = lane & 15, quad = lane >> 4;

    int len = lens[b];
    float b0 = bs[0];

    // zero the K-pad columns [400, LDH) once; staging never writes them
    for (int idx = tid; idx < NT * (LDH - D_); idx += 256) {
        int r = idx / (LDH - D_), c = idx % (LDH - D_);
        h_lds[r * LDH + D_ + c] = (bf16_t)0.0f;
    }

    // Preload A fragments (vals rows, f32 -> bf16) into registers.
    // A layout (16x16x32): A[m = lane&15][k = quad*8 + j]
    bf16x8 afrag[13];
    {
        const float* vrow = Cv + (size_t)(vbase + wave * 16 + lrow) * D_;
#pragma unroll
        for (int kk = 0; kk < 13; ++kk) {
            int k0 = kk * 32 + quad * 8;
            bf16x8 f;
            if (k0 >= D_) {
#pragma unroll
                for (int j = 0; j < 8; ++j) f[j] = (bf16_t)0.0f;
            } else {
                const float4* p = (const float4*)(vrow + k0);
                float4 x = p[0], y = p[1];
                f[0] = (bf16_t)x.x; f[1] = (bf16_t)x.y;
                f[2] = (bf16_t)x.z; f[3] = (bf16_t)x.w;
                f[4] = (bf16_t)y.x; f[5] = (bf16_t)y.y;
                f[6] = (bf16_t)y.z; f[7] = (bf16_t)y.w;
            }
            afrag[kk] = f;
        }
    }

    float m_s[4], l_s[4], a_s[4];
#pragma unroll
    for (int r = 0; r < 4; ++r) { m_s[r] = -3.0e38f; l_s[r] = 0.f; a_s[r] = 0.f; }

    int ntiles = (len + NT - 1) / NT;   // len >= T/2, wave-uniform per block
    const float* Hb = H + (size_t)b * T_ * D_;

    for (int tt = 0; tt < ntiles; ++tt) {
        int t0 = tt * NT;
        __syncthreads();
        // stage H tile 64 x 400 f32 -> bf16 LDS (coalesced float4 loads)
        for (int idx = tid; idx < NT * (D_ / 4); idx += 256) {
            int r = idx / (D_ / 4), c4 = idx % (D_ / 4);
            float4 x = *(const float4*)(Hb + (size_t)(t0 + r) * D_ + c4 * 4);
            bf16x4 f;
            f[0] = (bf16_t)x.x; f[1] = (bf16_t)x.y;
            f[2] = (bf16_t)x.z; f[3] = (bf16_t)x.w;
            *(bf16x4*)(&h_lds[r * LDH + c4 * 4]) = f;
        }
        if (tid < NT) hw_lds[tid] = hw[(size_t)b * T_ + t0 + tid];
        __syncthreads();

        // S tile: wave computes 16 v-rows x 64 t-cols (4 n-subtiles)
        floatx4 c[4];
        floatx4 zero4 = {0.f, 0.f, 0.f, 0.f};
#pragma unroll
        for (int s = 0; s < 4; ++s) c[s] = zero4;

#pragma unroll
        for (int kk = 0; kk < 13; ++kk) {
            int koff = kk * 32 + quad * 8;
#pragma unroll
            for (int s = 0; s < 4; ++s) {
                // B layout: B[k = quad*8+j][n = lane&15]; H is [t][k] = B^T rows
                const bf16x8* bp = (const bf16x8*)(&h_lds[(s * 16 + lrow) * LDH + koff]);
                c[s] = __builtin_amdgcn_mfma_f32_16x16x32_bf16(afrag[kk], *bp, c[s], 0, 0, 0);
            }
        }

        // C/D layout: col(t) = lane&15, row(v) = quad*4 + r
        bool full = (t0 + NT <= len);
        if (!full) {
#pragma unroll
            for (int s = 0; s < 4; ++s) {
                int t = t0 + s * 16 + lrow;
                if (t >= len) {
                    c[s][0] = -3.0e38f; c[s][1] = -3.0e38f;
                    c[s][2] = -3.0e38f; c[s][3] = -3.0e38f;
                }
            }
        }

        float tmax[4];
#pragma unroll
        for (int r = 0; r < 4; ++r)
            tmax[r] = fmaxf(fmaxf(c[0][r], c[1][r]), fmaxf(c[2][r], c[3][r]));
#pragma unroll
        for (int off = 1; off < 16; off <<= 1) {
#pragma unroll
            for (int r = 0; r < 4; ++r)
                tmax[r] = fmaxf(tmax[r], __shfl_xor(tmax[r], off, 64));
        }

        float hwv[4];
#pragma unroll
        for (int s = 0; s < 4; ++s) hwv[s] = hw_lds[s * 16 + lrow];

#pragma unroll
        for (int r = 0; r < 4; ++r) {
            float mn = fmaxf(m_s[r], tmax[r]);
            float alpha = __expf(m_s[r] - mn);
            float ps = 0.f, qs = 0.f;
#pragma unroll
            for (int s = 0; s < 4; ++s) {
                float p = __expf(c[s][r] - mn);   // masked cols -> exp(-huge) = 0
                ps += p;
                qs += p * hwv[s];
            }
#pragma unroll
            for (int off = 1; off < 16; off <<= 1) {
                ps += __shfl_xor(ps, off, 64);
                qs += __shfl_xor(qs, off, 64);
            }
            l_s[r] = l_s[r] * alpha + ps;
            a_s[r] = a_s[r] * alpha + qs;
            m_s[r] = mn;
        }
    }

    // epilogue: row r's state is replicated across the 16 lanes of its quad
    if (lrow == 0) {
#pragma unroll
        for (int r = 0; r < 4; ++r) {
            int v = vbase + wave * 16 + quad * 4 + r;
            float y = a_s[r] / l_s[r] + b0;
            out[(size_t)b * NV + v] = y;
        }
    }
}

// ---------------------------------------------------------------------------
extern "C" void kernel_launch(void* const* d_in, const int* in_sizes, int n_in,
                              void* d_out, int out_size, void* d_ws, size_t ws_size,
                              hipStream_t stream) {
    const float* H    = (const float*)d_in[0];   // (B,T,D)
    const float* cu   = (const float*)d_in[1];   // (B,D)
    const float* Ca   = (const float*)d_in[2];   // (B,NA,D)
    const float* Cv   = (const float*)d_in[3];   // (NV,1,D)
    const float* W    = (const float*)d_in[4];   // (1,D)
    const float* bs   = (const float*)d_in[5];   // (1,)
    const int*   lens = (const int*)d_in[6];     // (B,)
    float* out = (float*)d_out;                  // f32: y_utts (B,NV) ++ y_acts (B,NV)

    float* hw   = (float*)d_ws;            // B*T f32   (256 KB)
    float* q_ws = hw + (size_t)B_ * T_;    // B*D f32   (200 KB)

    hw_kernel<<<dim3(B_ * T_ / 4), dim3(256), 0, stream>>>(H, W, hw);
    acts_kernel<<<dim3(B_), dim3(256), 0, stream>>>(Ca, cu, q_ws);
    main_kernel<<<dim3(2048), dim3(256), 0, stream>>>(H, Cv, hw, bs, lens, out);
    yacts_kernel<<<dim3(4, B_), dim3(256), 0, stream>>>(q_ws, Cv, out);
}

// Round 3
// 378.903 us; speedup vs baseline: 1.5973x; 1.5973x over previous
//
#include <hip/hip_runtime.h>
#include <hip/hip_bf16.h>

// Problem constants
#define B_  128
#define T_  512
#define D_  400
#define NV  1024
#define NA  128

// Main-kernel tiling
#define LDH  424   // LDS/Hbf row stride (bf16): 848 B = 53*16, 2-way-conflict-free
#define NT   64    // t-tile
#define MV   128   // v rows per block (4 waves x 32)

typedef __bf16 bf16_t;
typedef bf16_t bf16x8 __attribute__((ext_vector_type(8)));
typedef bf16_t bf16x4 __attribute__((ext_vector_type(4)));
typedef float  floatx4 __attribute__((ext_vector_type(4)));

__device__ inline void async_copy16(const void* g, void* l) {
    __builtin_amdgcn_global_load_lds(
        (const __attribute__((address_space(1))) unsigned int*)g,
        (__attribute__((address_space(3))) unsigned int*)l, 16, 0, 0);
}

// ---------------------------------------------------------------------------
// Kernel 1a (fast path): hw[b,t] = H[b,t,:].W  AND  Hbf[row] = bf16(H row),
// padded to 424 cols with zeros. One wave per row.
// ---------------------------------------------------------------------------
__global__ __launch_bounds__(256) void hw_prep_kernel(const float* __restrict__ H,
                                                      const float* __restrict__ W,
                                                      float* __restrict__ hw,
                                                      bf16_t* __restrict__ Hbf) {
    int wave = threadIdx.x >> 6;
    int lane = threadIdx.x & 63;
    long row = (long)blockIdx.x * 4 + wave;          // [0, B*T)
    const float* h = H + row * D_;
    bf16_t* orow = Hbf + row * (long)LDH;
    float acc = 0.f;
    if (lane < 50) {
        const float4* p  = (const float4*)(h + lane * 8);
        const float4* wp = (const float4*)(W + lane * 8);
        float4 x = p[0], y = p[1];
        float4 wx = wp[0], wy = wp[1];
        acc = x.x * wx.x + x.y * wx.y + x.z * wx.z + x.w * wx.w
            + y.x * wy.x + y.y * wy.y + y.z * wy.z + y.w * wy.w;
        bf16x8 f;
        f[0] = (bf16_t)x.x; f[1] = (bf16_t)x.y; f[2] = (bf16_t)x.z; f[3] = (bf16_t)x.w;
        f[4] = (bf16_t)y.x; f[5] = (bf16_t)y.y; f[6] = (bf16_t)y.z; f[7] = (bf16_t)y.w;
        *(bf16x8*)(orow + lane * 8) = f;
    } else if (lane < 53) {
        bf16x8 z;
#pragma unroll
        for (int j = 0; j < 8; ++j) z[j] = (bf16_t)0.0f;
        *(bf16x8*)(orow + 400 + (lane - 50) * 8) = z;
    }
#pragma unroll
    for (int off = 1; off < 64; off <<= 1) acc += __shfl_xor(acc, off, 64);
    if (lane == 0) hw[row] = acc;
}

// ---------------------------------------------------------------------------
// Kernel 1b (fallback): hw only
// ---------------------------------------------------------------------------
__global__ __launch_bounds__(256) void hw_kernel(const float* __restrict__ H,
                                                 const float* __restrict__ W,
                                                 float* __restrict__ hw) {
    int wave = threadIdx.x >> 6;
    int lane = threadIdx.x & 63;
    long row = (long)blockIdx.x * 4 + wave;
    const float* h = H + row * D_;
    float acc = 0.f;
    for (int k = lane; k < D_; k += 64) acc += h[k] * W[k];
#pragma unroll
    for (int off = 1; off < 64; off <<= 1) acc += __shfl_xor(acc, off, 64);
    if (lane == 0) hw[row] = acc;
}

// ---------------------------------------------------------------------------
// Kernel 2: per-b acts softmax -> q_acts[b,:] into workspace
// ---------------------------------------------------------------------------
__global__ __launch_bounds__(256) void acts_kernel(const float* __restrict__ Ca,
                                                   const float* __restrict__ cu,
                                                   float* __restrict__ q_ws) {
    __shared__ float c_lds[D_];
    __shared__ float p_lds[NA];
    int b = blockIdx.x;
    int tid = threadIdx.x, wave = tid >> 6, lane = tid & 63;

    for (int d = tid; d < D_; d += 256) c_lds[d] = cu[b * D_ + d];
    __syncthreads();

    const float* Cb = Ca + (size_t)b * NA * D_;
    for (int a = wave * 32; a < wave * 32 + 32; ++a) {
        float acc = 0.f;
        for (int k = lane; k < D_; k += 64) acc += Cb[(size_t)a * D_ + k] * c_lds[k];
#pragma unroll
        for (int off = 1; off < 64; off <<= 1) acc += __shfl_xor(acc, off, 64);
        if (lane == 0) p_lds[a] = acc;
    }
    __syncthreads();

    if (tid < 64) {
        float v0 = p_lds[tid], v1 = p_lds[tid + 64];
        float m = fmaxf(v0, v1);
#pragma unroll
        for (int off = 1; off < 64; off <<= 1) m = fmaxf(m, __shfl_xor(m, off, 64));
        float e0 = __expf(v0 - m), e1 = __expf(v1 - m);
        float s = e0 + e1;
#pragma unroll
        for (int off = 1; off < 64; off <<= 1) s += __shfl_xor(s, off, 64);
        p_lds[tid] = e0 / s;
        p_lds[tid + 64] = e1 / s;
    }
    __syncthreads();

    for (int d = tid; d < D_; d += 256) {
        float acc = 0.f;
#pragma unroll 8
        for (int a = 0; a < NA; ++a) acc += p_lds[a] * Cb[(size_t)a * D_ + d];
        q_ws[b * D_ + d] = acc;
    }
}

// ---------------------------------------------------------------------------
// Kernel 3: y_acts[b,v] = q_acts[b,:].vals[v,:]  — wave per row (coalesced)
// ---------------------------------------------------------------------------
__global__ __launch_bounds__(256) void yacts_kernel(const float* __restrict__ q_ws,
                                                    const float* __restrict__ Cv,
                                                    float* __restrict__ out) {
    int wave = threadIdx.x >> 6;
    int lane = threadIdx.x & 63;
    long row = (long)blockIdx.x * 4 + wave;          // [0, B*NV)
    int b = (int)(row >> 10);
    int v = (int)(row & 1023);
    const float4* v4 = (const float4*)(Cv + (size_t)v * D_);
    const float4* q4 = (const float4*)(q_ws + (size_t)b * D_);
    float acc = 0.f;
    for (int j = lane; j < D_ / 4; j += 64) {
        float4 x = v4[j], y = q4[j];
        acc += x.x * y.x + x.y * y.y + x.z * y.z + x.w * y.w;
    }
#pragma unroll
    for (int off = 1; off < 64; off <<= 1) acc += __shfl_xor(acc, off, 64);
    if (lane == 0) out[(size_t)B_ * NV + row] = acc;
}

// ---------------------------------------------------------------------------
// Main kernel: flash-style scalar-value attention.
// Block = (b, 128-v chunk). 4 waves x 32 v-rows (2 A-sets). Loop t in 64-tiles.
// PRE=1: H pre-converted to bf16 (Hbf, 424-stride) -> global_load_lds staging.
// PRE=0: stage from f32 H with in-kernel conversion.
// Per-lane online softmax (no cross-lane ops in loop); butterfly merge at end.
// ---------------------------------------------------------------------------
template<int PRE>
__global__ __launch_bounds__(256, 2) void main_kernel(const float* __restrict__ H,
                                                      const bf16_t* __restrict__ Hbf,
                                                      const float* __restrict__ Cv,
                                                      const float* __restrict__ hw,
                                                      const float* __restrict__ bs,
                                                      const int* __restrict__ lens,
                                                      float* __restrict__ out) {
    __shared__ bf16_t h_lds[NT * LDH];
    __shared__ float hw_lds[NT];

    // XCD swizzle: the 8 v-chunks of one b land on one XCD (i%8 = XCD id
    // heuristic) so H[b] stays L2-resident across re-reads.
    int i = blockIdx.x;
    int xcd = i & 7, vc = (i >> 3) & 7, bb = i >> 6;
    int b = xcd + 8 * bb;            // 0..127
    int vbase = vc * MV;             // 8 chunks of 128

    int tid = threadIdx.x;
    int wave = tid >> 6, lane = tid & 63;
    int lrow = lane & 15, quad = lane >> 4;

    int len = lens[b];
    float b0 = bs[0];

    if (!PRE) {
        // zero the K-pad columns [400, 424) once; staging never writes them
        for (int idx = tid; idx < NT * (LDH - D_); idx += 256) {
            int r = idx / (LDH - D_), c = idx % (LDH - D_);
            h_lds[r * LDH + D_ + c] = (bf16_t)0.0f;
        }
    }

    // Preload A fragments: 2 sets x 13 k-steps (vals rows, f32 -> bf16).
    // A layout (16x16x32): A[m = lane&15][k = quad*8 + j]
    bf16x8 afrag[2][13];
#pragma unroll
    for (int set = 0; set < 2; ++set) {
        const float* vrow = Cv + (size_t)(vbase + wave * 32 + set * 16 + lrow) * D_;
#pragma unroll
        for (int kk = 0; kk < 13; ++kk) {
            int k0 = kk * 32 + quad * 8;
            bf16x8 f;
            if (k0 >= D_) {
#pragma unroll
                for (int j = 0; j < 8; ++j) f[j] = (bf16_t)0.0f;
            } else {
                const float4* p = (const float4*)(vrow + k0);
                float4 x = p[0], y = p[1];
                f[0] = (bf16_t)x.x; f[1] = (bf16_t)x.y;
                f[2] = (bf16_t)x.z; f[3] = (bf16_t)x.w;
                f[4] = (bf16_t)y.x; f[5] = (bf16_t)y.y;
                f[6] = (bf16_t)y.z; f[7] = (bf16_t)y.w;
            }
            afrag[set][kk] = f;
        }
    }

    // per-lane online-softmax state: row = set*16 + quad*4 + r, cols t%16==lrow
    float m_s[2][4], l_s[2][4], a_s[2][4];
#pragma unroll
    for (int set = 0; set < 2; ++set)
#pragma unroll
        for (int r = 0; r < 4; ++r) { m_s[set][r] = -3.0e38f; l_s[set][r] = 0.f; a_s[set][r] = 0.f; }

    int ntiles = (len + NT - 1) / NT;   // len >= T/2, uniform per block
    const float* Hb = H + (size_t)b * T_ * D_;
    const bf16_t* Hbfb = Hbf + (size_t)b * T_ * LDH;

    for (int tt = 0; tt < ntiles; ++tt) {
        int t0 = tt * NT;
        __syncthreads();
        if (PRE) {
            // tile = contiguous 64*848 B = 53 chunks of 1024 B; DMA to LDS
            const char* gt = (const char*)(Hbfb + (size_t)t0 * LDH);
            char* lt = (char*)h_lds;
#pragma unroll 1
            for (int c = wave; c < 53; c += 4)
                async_copy16(gt + c * 1024 + lane * 16, lt + c * 1024 + lane * 16);
        } else {
            for (int idx = tid; idx < NT * (D_ / 4); idx += 256) {
                int r = idx / (D_ / 4), c4 = idx % (D_ / 4);
                float4 x = *(const float4*)(Hb + (size_t)(t0 + r) * D_ + c4 * 4);
                bf16x4 f;
                f[0] = (bf16_t)x.x; f[1] = (bf16_t)x.y;
                f[2] = (bf16_t)x.z; f[3] = (bf16_t)x.w;
                *(bf16x4*)(&h_lds[r * LDH + c4 * 4]) = f;
            }
        }
        if (tid < NT) hw_lds[tid] = hw[(size_t)b * T_ + t0 + tid];
        __syncthreads();

        // S tile: wave computes 32 v-rows x 64 t-cols; one B-read feeds 2 MFMAs
        floatx4 c[2][4];
        floatx4 zero4 = {0.f, 0.f, 0.f, 0.f};
#pragma unroll
        for (int set = 0; set < 2; ++set)
#pragma unroll
            for (int s = 0; s < 4; ++s) c[set][s] = zero4;

#pragma unroll
        for (int kk = 0; kk < 13; ++kk) {
            int koff = kk * 32 + quad * 8;
#pragma unroll
            for (int s = 0; s < 4; ++s) {
                bf16x8 bfr = *(const bf16x8*)(&h_lds[(s * 16 + lrow) * LDH + koff]);
                c[0][s] = __builtin_amdgcn_mfma_f32_16x16x32_bf16(afrag[0][kk], bfr, c[0][s], 0, 0, 0);
                c[1][s] = __builtin_amdgcn_mfma_f32_16x16x32_bf16(afrag[1][kk], bfr, c[1][s], 0, 0, 0);
            }
        }

        // mask tail cols (col t = t0 + s*16 + lrow)
        if (t0 + NT > len) {
#pragma unroll
            for (int s = 0; s < 4; ++s) {
                int t = t0 + s * 16 + lrow;
                if (t >= len) {
#pragma unroll
                    for (int set = 0; set < 2; ++set) {
                        c[set][s][0] = -3.0e38f; c[set][s][1] = -3.0e38f;
                        c[set][s][2] = -3.0e38f; c[set][s][3] = -3.0e38f;
                    }
                }
            }
        }

        float hwv[4];
#pragma unroll
        for (int s = 0; s < 4; ++s) hwv[s] = hw_lds[s * 16 + lrow];

        // per-lane online softmax update — no cross-lane traffic
#pragma unroll
        for (int set = 0; set < 2; ++set)
#pragma unroll
            for (int r = 0; r < 4; ++r) {
                float cm = fmaxf(fmaxf(c[set][0][r], c[set][1][r]),
                                 fmaxf(c[set][2][r], c[set][3][r]));
                float mn = fmaxf(m_s[set][r], cm);
                float alpha = __expf(m_s[set][r] - mn);
                float ps = 0.f, qs = 0.f;
#pragma unroll
                for (int s = 0; s < 4; ++s) {
                    float p = __expf(c[set][s][r] - mn);
                    ps += p;
                    qs += p * hwv[s];
                }
                l_s[set][r] = l_s[set][r] * alpha + ps;
                a_s[set][r] = a_s[set][r] * alpha + qs;
                m_s[set][r] = mn;
            }
    }

    // epilogue: merge the 16 per-lane partial softmax states within each quad
#pragma unroll
    for (int set = 0; set < 2; ++set)
#pragma unroll
        for (int r = 0; r < 4; ++r) {
            float m = m_s[set][r], l = l_s[set][r], a = a_s[set][r];
#pragma unroll
            for (int off = 1; off < 16; off <<= 1) {
                float mo = __shfl_xor(m, off, 64);
                float lo = __shfl_xor(l, off, 64);
                float ao = __shfl_xor(a, off, 64);
                float mn = fmaxf(m, mo);
                float f1 = __expf(m - mn), f2 = __expf(mo - mn);
                l = l * f1 + lo * f2;
                a = a * f1 + ao * f2;
                m = mn;
            }
            if (lrow == 0) {
                int v = vbase + wave * 32 + set * 16 + quad * 4 + r;
                out[(size_t)b * NV + v] = a / l + b0;
            }
        }
}

// ---------------------------------------------------------------------------
extern "C" void kernel_launch(void* const* d_in, const int* in_sizes, int n_in,
                              void* d_out, int out_size, void* d_ws, size_t ws_size,
                              hipStream_t stream) {
    const float* H    = (const float*)d_in[0];   // (B,T,D)
    const float* cu   = (const float*)d_in[1];   // (B,D)
    const float* Ca   = (const float*)d_in[2];   // (B,NA,D)
    const float* Cv   = (const float*)d_in[3];   // (NV,1,D)
    const float* W    = (const float*)d_in[4];   // (1,D)
    const float* bs   = (const float*)d_in[5];   // (1,)
    const int*   lens = (const int*)d_in[6];     // (B,)
    float* out = (float*)d_out;                  // f32: y_utts (B,NV) ++ y_acts (B,NV)

    float*  hw   = (float*)d_ws;                       // B*T f32 (512 KB)
    float*  q_ws = hw + (size_t)B_ * T_;               // B*D f32 (200 KB)
    bf16_t* Hbf  = (bf16_t*)(q_ws + (size_t)B_ * D_);  // B*T*424 bf16 (55.6 MB)

    size_t need = ((size_t)B_ * T_ + (size_t)B_ * D_) * sizeof(float)
                + (size_t)B_ * T_ * LDH * sizeof(bf16_t);
    bool pre = (ws_size >= need);

    if (pre) {
        hw_prep_kernel<<<dim3(B_ * T_ / 4), dim3(256), 0, stream>>>(H, W, hw, Hbf);
    } else {
        hw_kernel<<<dim3(B_ * T_ / 4), dim3(256), 0, stream>>>(H, W, hw);
    }
    acts_kernel<<<dim3(B_), dim3(256), 0, stream>>>(Ca, cu, q_ws);
    if (pre) {
        main_kernel<1><<<dim3(1024), dim3(256), 0, stream>>>(H, Hbf, Cv, hw, bs, lens, out);
    } else {
        main_kernel<0><<<dim3(1024), dim3(256), 0, stream>>>(H, Hbf, Cv, hw, bs, lens, out);
    }
    yacts_kernel<<<dim3(B_ * NV / 4), dim3(256), 0, stream>>>(q_ws, Cv, out);
}

// Round 5
// 279.523 us; speedup vs baseline: 2.1652x; 1.3555x over previous
//
#include <hip/hip_runtime.h>
#include <hip/hip_bf16.h>

// Problem constants
#define B_  128
#define T_  512
#define D_  400
#define NV  1024
#define NA  128

// Main-kernel tiling
#define LDH  424   // LDS/Hbf row stride (bf16): 848 B = 53*16
#define NT   64    // t-tile
#define MV   128   // v rows per block (4 waves x 32)

typedef __bf16 bf16_t;
typedef bf16_t bf16x8 __attribute__((ext_vector_type(8)));
typedef bf16_t bf16x4 __attribute__((ext_vector_type(4)));
typedef float  floatx4 __attribute__((ext_vector_type(4)));

__device__ inline void async_copy16(const void* g, void* l) {
    __builtin_amdgcn_global_load_lds(
        (const __attribute__((address_space(1))) unsigned int*)g,
        (__attribute__((address_space(3))) unsigned int*)l, 16, 0, 0);
}

__device__ inline float dot4(float4 a, float4 b) {
    return a.x * b.x + a.y * b.y + a.z * b.z + a.w * b.w;
}

// ---------------------------------------------------------------------------
// Kernel 1a (fast path): hw[b,t] = H[b,t,:].W  AND  Hbf[row] = bf16(H row),
// padded to 424 cols with zeros. One wave per row.
// ---------------------------------------------------------------------------
__global__ __launch_bounds__(256) void hw_prep_kernel(const float* __restrict__ H,
                                                      const float* __restrict__ W,
                                                      float* __restrict__ hw,
                                                      bf16_t* __restrict__ Hbf) {
    int wave = threadIdx.x >> 6;
    int lane = threadIdx.x & 63;
    long row = (long)blockIdx.x * 4 + wave;          // [0, B*T)
    const float* h = H + row * D_;
    bf16_t* orow = Hbf + row * (long)LDH;
    float acc = 0.f;
    if (lane < 50) {
        const float4* p  = (const float4*)(h + lane * 8);
        const float4* wp = (const float4*)(W + lane * 8);
        float4 x = p[0], y = p[1];
        float4 wx = wp[0], wy = wp[1];
        acc = dot4(x, wx) + dot4(y, wy);
        bf16x8 f;
        f[0] = (bf16_t)x.x; f[1] = (bf16_t)x.y; f[2] = (bf16_t)x.z; f[3] = (bf16_t)x.w;
        f[4] = (bf16_t)y.x; f[5] = (bf16_t)y.y; f[6] = (bf16_t)y.z; f[7] = (bf16_t)y.w;
        *(bf16x8*)(orow + lane * 8) = f;
    } else if (lane < 53) {
        bf16x8 z;
#pragma unroll
        for (int j = 0; j < 8; ++j) z[j] = (bf16_t)0.0f;
        *(bf16x8*)(orow + 400 + (lane - 50) * 8) = z;
    }
#pragma unroll
    for (int off = 1; off < 64; off <<= 1) acc += __shfl_xor(acc, off, 64);
    if (lane == 0) hw[row] = acc;
}

// ---------------------------------------------------------------------------
// Kernel 1b (fallback): hw only
// ---------------------------------------------------------------------------
__global__ __launch_bounds__(256) void hw_kernel(const float* __restrict__ H,
                                                 const float* __restrict__ W,
                                                 float* __restrict__ hw) {
    int wave = threadIdx.x >> 6;
    int lane = threadIdx.x & 63;
    long row = (long)blockIdx.x * 4 + wave;
    const float* h = H + row * D_;
    float acc = 0.f;
    for (int k = lane; k < D_; k += 64) acc += h[k] * W[k];
#pragma unroll
    for (int off = 1; off < 64; off <<= 1) acc += __shfl_xor(acc, off, 64);
    if (lane == 0) hw[row] = acc;
}

// ---------------------------------------------------------------------------
// Kernel 2a: s2[b,a] = C_acts[b,a,:] . c_utt[b,:]  — one wave per (b,a) row.
// ---------------------------------------------------------------------------
__global__ __launch_bounds__(256) void s2_kernel(const float* __restrict__ Ca,
                                                 const float* __restrict__ cu,
                                                 float* __restrict__ s2) {
    int wave = threadIdx.x >> 6;
    int lane = threadIdx.x & 63;
    long row = (long)blockIdx.x * 4 + wave;          // [0, B*NA)
    int b = (int)(row >> 7);
    const float4* a4 = (const float4*)(Ca + row * (long)D_);
    const float4* c4 = (const float4*)(cu + (long)b * D_);
    float acc = dot4(a4[lane], c4[lane]);            // cols 0..63
    if (lane < 36) acc += dot4(a4[lane + 64], c4[lane + 64]);  // cols 64..99
#pragma unroll
    for (int off = 1; off < 64; off <<= 1) acc += __shfl_xor(acc, off, 64);
    if (lane == 0) s2[row] = acc;
}

// ---------------------------------------------------------------------------
// Kernel 2b: per-b softmax of s2 + q_acts[b,:] = sum_a p[a] * C_acts[b,a,:]
// Block per b. ALL __syncthreads() in uniform control flow (round-4 bugfix:
// wave 3 diverged at tid<200 and executed the barrier twice -> race on part[]).
// ---------------------------------------------------------------------------
__global__ __launch_bounds__(256) void qacts_kernel(const float* __restrict__ s2,
                                                    const float* __restrict__ Ca,
                                                    float* __restrict__ q_ws) {
    __shared__ float p_lds[NA];
    __shared__ float red[8];
    __shared__ __align__(16) float4 part[100];
    int b = blockIdx.x;
    int tid = threadIdx.x, wave = tid >> 6, lane = tid & 63;

    // Phase A: softmax over the 128 scores (threads 0..127 carry data)
    float s = (tid < NA) ? s2[(long)b * NA + tid] : -3.0e38f;
    float m = s;
#pragma unroll
    for (int off = 1; off < 64; off <<= 1) m = fmaxf(m, __shfl_xor(m, off, 64));
    if (lane == 0) red[wave] = m;
    __syncthreads();
    m = fmaxf(red[0], red[1]);
    float e = (tid < NA) ? __expf(s - m) : 0.f;
    float sum = e;
#pragma unroll
    for (int off = 1; off < 64; off <<= 1) sum += __shfl_xor(sum, off, 64);
    if (lane == 0) red[4 + wave] = sum;
    __syncthreads();
    float S = red[4] + red[5];
    if (tid < NA) p_lds[tid] = e / S;
    __syncthreads();

    // Phase B: q[b, 4c..4c+3] — thread t<200: c4 = t%100, a-half = t/100.
    // Barriers hoisted out of the divergent region; work is predicated.
    int c4 = tid % 100;
    int half = tid / 100;            // 0,1 carry data; 2 = idle tail
    float4 acc0 = {0.f, 0.f, 0.f, 0.f};
    if (tid < 200) {
        const float4* Cb4 = (const float4*)(Ca + (size_t)b * NA * D_);
        float4 acc1 = {0.f, 0.f, 0.f, 0.f};
        int a0 = half * 64;
#pragma unroll 4
        for (int a = 0; a < 64; a += 2) {
            float p0 = p_lds[a0 + a], p1 = p_lds[a0 + a + 1];
            float4 x0 = Cb4[(size_t)(a0 + a) * 100 + c4];
            float4 x1 = Cb4[(size_t)(a0 + a + 1) * 100 + c4];
            acc0.x += p0 * x0.x; acc0.y += p0 * x0.y; acc0.z += p0 * x0.z; acc0.w += p0 * x0.w;
            acc1.x += p1 * x1.x; acc1.y += p1 * x1.y; acc1.z += p1 * x1.z; acc1.w += p1 * x1.w;
        }
        acc0.x += acc1.x; acc0.y += acc1.y; acc0.z += acc1.z; acc0.w += acc1.w;
        if (half == 1) part[c4] = acc0;
    }
    __syncthreads();
    if (tid < 100) {
        float4 o = part[c4];
        o.x += acc0.x; o.y += acc0.y; o.z += acc0.z; o.w += acc0.w;
        ((float4*)(q_ws + (size_t)b * D_))[c4] = o;
    }
}

// ---------------------------------------------------------------------------
// Kernel 3: y_acts — one wave per 4 v-rows (4 interleaved dot/reduce chains)
// ---------------------------------------------------------------------------
__global__ __launch_bounds__(256) void yacts_kernel(const float* __restrict__ q_ws,
                                                    const float* __restrict__ Cv,
                                                    float* __restrict__ out) {
    int wave = threadIdx.x >> 6;
    int lane = threadIdx.x & 63;
    long grp = (long)blockIdx.x * 4 + wave;          // [0, B*NV/4)
    int b = (int)(grp >> 8);                         // 256 groups per b
    int v0 = (int)(grp & 255) * 4;
    const float4* q4 = (const float4*)(q_ws + (size_t)b * D_);
    float4 qa = q4[lane];
    float4 qb = (lane < 36) ? q4[lane + 64] : make_float4(0.f, 0.f, 0.f, 0.f);
    float acc[4];
#pragma unroll
    for (int r = 0; r < 4; ++r) {
        const float4* v4 = (const float4*)(Cv + (size_t)(v0 + r) * D_);
        float4 x = v4[lane];
        acc[r] = dot4(x, qa);
        if (lane < 36) acc[r] += dot4(v4[lane + 64], qb);
    }
#pragma unroll
    for (int off = 1; off < 64; off <<= 1) {
#pragma unroll
        for (int r = 0; r < 4; ++r) acc[r] += __shfl_xor(acc[r], off, 64);
    }
    if (lane == 0) {
        float4 o = make_float4(acc[0], acc[1], acc[2], acc[3]);
        *(float4*)(out + (size_t)B_ * NV + (size_t)b * NV + v0) = o;
    }
}

// ---------------------------------------------------------------------------
// Main kernel: flash-style scalar-value attention (unchanged).
// ---------------------------------------------------------------------------
template<int PRE>
__global__ __launch_bounds__(256, 2) void main_kernel(const float* __restrict__ H,
                                                      const bf16_t* __restrict__ Hbf,
                                                      const float* __restrict__ Cv,
                                                      const float* __restrict__ hw,
                                                      const float* __restrict__ bs,
                                                      const int* __restrict__ lens,
                                                      float* __restrict__ out) {
    __shared__ bf16_t h_lds[NT * LDH];
    __shared__ float hw_lds[NT];

    int i = blockIdx.x;
    int xcd = i & 7, vc = (i >> 3) & 7, bb = i >> 6;
    int b = xcd + 8 * bb;            // 0..127
    int vbase = vc * MV;             // 8 chunks of 128

    int tid = threadIdx.x;
    int wave = tid >> 6, lane = tid & 63;
    int lrow = lane & 15, quad = lane >> 4;

    int len = lens[b];
    float b0 = bs[0];

    if (!PRE) {
        for (int idx = tid; idx < NT * (LDH - D_); idx += 256) {
            int r = idx / (LDH - D_), c = idx % (LDH - D_);
            h_lds[r * LDH + D_ + c] = (bf16_t)0.0f;
        }
    }

    bf16x8 afrag[2][13];
#pragma unroll
    for (int set = 0; set < 2; ++set) {
        const float* vrow = Cv + (size_t)(vbase + wave * 32 + set * 16 + lrow) * D_;
#pragma unroll
        for (int kk = 0; kk < 13; ++kk) {
            int k0 = kk * 32 + quad * 8;
            bf16x8 f;
            if (k0 >= D_) {
#pragma unroll
                for (int j = 0; j < 8; ++j) f[j] = (bf16_t)0.0f;
            } else {
                const float4* p = (const float4*)(vrow + k0);
                float4 x = p[0], y = p[1];
                f[0] = (bf16_t)x.x; f[1] = (bf16_t)x.y;
                f[2] = (bf16_t)x.z; f[3] = (bf16_t)x.w;
                f[4] = (bf16_t)y.x; f[5] = (bf16_t)y.y;
                f[6] = (bf16_t)y.z; f[7] = (bf16_t)y.w;
            }
            afrag[set][kk] = f;
        }
    }

    float m_s[2][4], l_s[2][4], a_s[2][4];
#pragma unroll
    for (int set = 0; set < 2; ++set)
#pragma unroll
        for (int r = 0; r < 4; ++r) { m_s[set][r] = -3.0e38f; l_s[set][r] = 0.f; a_s[set][r] = 0.f; }

    int ntiles = (len + NT - 1) / NT;
    const float* Hb = H + (size_t)b * T_ * D_;
    const bf16_t* Hbfb = Hbf + (size_t)b * T_ * LDH;

    for (int tt = 0; tt < ntiles; ++tt) {
        int t0 = tt * NT;
        __syncthreads();
        if (PRE) {
            const char* gt = (const char*)(Hbfb + (size_t)t0 * LDH);
            char* lt = (char*)h_lds;
#pragma unroll 1
            for (int c = wave; c < 53; c += 4)
                async_copy16(gt + c * 1024 + lane * 16, lt + c * 1024 + lane * 16);
        } else {
            for (int idx = tid; idx < NT * (D_ / 4); idx += 256) {
                int r = idx / (D_ / 4), c4 = idx % (D_ / 4);
                float4 x = *(const float4*)(Hb + (size_t)(t0 + r) * D_ + c4 * 4);
                bf16x4 f;
                f[0] = (bf16_t)x.x; f[1] = (bf16_t)x.y;
                f[2] = (bf16_t)x.z; f[3] = (bf16_t)x.w;
                *(bf16x4*)(&h_lds[r * LDH + c4 * 4]) = f;
            }
        }
        if (tid < NT) hw_lds[tid] = hw[(size_t)b * T_ + t0 + tid];
        __syncthreads();

        floatx4 c[2][4];
        floatx4 zero4 = {0.f, 0.f, 0.f, 0.f};
#pragma unroll
        for (int set = 0; set < 2; ++set)
#pragma unroll
            for (int s = 0; s < 4; ++s) c[set][s] = zero4;

#pragma unroll
        for (int kk = 0; kk < 13; ++kk) {
            int koff = kk * 32 + quad * 8;
#pragma unroll
            for (int s = 0; s < 4; ++s) {
                bf16x8 bfr = *(const bf16x8*)(&h_lds[(s * 16 + lrow) * LDH + koff]);
                c[0][s] = __builtin_amdgcn_mfma_f32_16x16x32_bf16(afrag[0][kk], bfr, c[0][s], 0, 0, 0);
                c[1][s] = __builtin_amdgcn_mfma_f32_16x16x32_bf16(afrag[1][kk], bfr, c[1][s], 0, 0, 0);
            }
        }

        if (t0 + NT > len) {
#pragma unroll
            for (int s = 0; s < 4; ++s) {
                int t = t0 + s * 16 + lrow;
                if (t >= len) {
#pragma unroll
                    for (int set = 0; set < 2; ++set) {
                        c[set][s][0] = -3.0e38f; c[set][s][1] = -3.0e38f;
                        c[set][s][2] = -3.0e38f; c[set][s][3] = -3.0e38f;
                    }
                }
            }
        }

        float hwv[4];
#pragma unroll
        for (int s = 0; s < 4; ++s) hwv[s] = hw_lds[s * 16 + lrow];

#pragma unroll
        for (int set = 0; set < 2; ++set)
#pragma unroll
            for (int r = 0; r < 4; ++r) {
                float cm = fmaxf(fmaxf(c[set][0][r], c[set][1][r]),
                                 fmaxf(c[set][2][r], c[set][3][r]));
                float mn = fmaxf(m_s[set][r], cm);
                float alpha = __expf(m_s[set][r] - mn);
                float ps = 0.f, qs = 0.f;
#pragma unroll
                for (int s = 0; s < 4; ++s) {
                    float p = __expf(c[set][s][r] - mn);
                    ps += p;
                    qs += p * hwv[s];
                }
                l_s[set][r] = l_s[set][r] * alpha + ps;
                a_s[set][r] = a_s[set][r] * alpha + qs;
                m_s[set][r] = mn;
            }
    }

#pragma unroll
    for (int set = 0; set < 2; ++set)
#pragma unroll
        for (int r = 0; r < 4; ++r) {
            float m = m_s[set][r], l = l_s[set][r], a = a_s[set][r];
#pragma unroll
            for (int off = 1; off < 16; off <<= 1) {
                float mo = __shfl_xor(m, off, 64);
                float lo = __shfl_xor(l, off, 64);
                float ao = __shfl_xor(a, off, 64);
                float mn = fmaxf(m, mo);
                float f1 = __expf(m - mn), f2 = __expf(mo - mn);
                l = l * f1 + lo * f2;
                a = a * f1 + ao * f2;
                m = mn;
            }
            if (lrow == 0) {
                int v = vbase + wave * 32 + set * 16 + quad * 4 + r;
                out[(size_t)b * NV + v] = a / l + b0;
            }
        }
}

// ---------------------------------------------------------------------------
extern "C" void kernel_launch(void* const* d_in, const int* in_sizes, int n_in,
                              void* d_out, int out_size, void* d_ws, size_t ws_size,
                              hipStream_t stream) {
    const float* H    = (const float*)d_in[0];   // (B,T,D)
    const float* cu   = (const float*)d_in[1];   // (B,D)
    const float* Ca   = (const float*)d_in[2];   // (B,NA,D)
    const float* Cv   = (const float*)d_in[3];   // (NV,1,D)
    const float* W    = (const float*)d_in[4];   // (1,D)
    const float* bs   = (const float*)d_in[5];   // (1,)
    const int*   lens = (const int*)d_in[6];     // (B,)
    float* out = (float*)d_out;                  // f32: y_utts (B,NV) ++ y_acts (B,NV)

    float*  hw   = (float*)d_ws;                        // B*T f32 (256 KB)
    float*  q_ws = hw + (size_t)B_ * T_;                // B*D f32 (200 KB)
    float*  s2   = q_ws + (size_t)B_ * D_;              // B*NA f32 (64 KB)
    bf16_t* Hbf  = (bf16_t*)(s2 + (size_t)B_ * NA);     // B*T*424 bf16 (55.6 MB)

    size_t need = ((size_t)B_ * T_ + (size_t)B_ * D_ + (size_t)B_ * NA) * sizeof(float)
                + (size_t)B_ * T_ * LDH * sizeof(bf16_t);
    bool pre = (ws_size >= need);

    if (pre) {
        hw_prep_kernel<<<dim3(B_ * T_ / 4), dim3(256), 0, stream>>>(H, W, hw, Hbf);
    } else {
        hw_kernel<<<dim3(B_ * T_ / 4), dim3(256), 0, stream>>>(H, W, hw);
    }
    s2_kernel<<<dim3(B_ * NA / 4), dim3(256), 0, stream>>>(Ca, cu, s2);
    qacts_kernel<<<dim3(B_), dim3(256), 0, stream>>>(s2, Ca, q_ws);
    if (pre) {
        main_kernel<1><<<dim3(1024), dim3(256), 0, stream>>>(H, Hbf, Cv, hw, bs, lens, out);
    } else {
        main_kernel<0><<<dim3(1024), dim3(256), 0, stream>>>(H, Hbf, Cv, hw, bs, lens, out);
    }
    yacts_kernel<<<dim3(B_ * NV / 16), dim3(256), 0, stream>>>(q_ws, Cv, out);
}